// Round 6
// baseline (649.722 us; speedup 1.0000x reference)
//
#include <hip/hip_runtime.h>
#include <stdint.h>

typedef __attribute__((ext_vector_type(8))) short short8;
typedef __attribute__((ext_vector_type(4))) float floatx4;
typedef unsigned short u16;
typedef unsigned int u32;

#define MFMA16(a,b,c) __builtin_amdgcn_mfma_f32_16x16x32_bf16((a),(b),(c),0,0,0)

__device__ __forceinline__ u16 f2b(float f){
  u32 i; __builtin_memcpy(&i,&f,4); i += 0x7FFFu + ((i>>16)&1u); return (u16)(i>>16);
}
__device__ __forceinline__ u32 pk2(float a, float b){
  return (u32)f2b(a) | ((u32)f2b(b)<<16);
}
__device__ __forceinline__ int regid(int p){ return (p<56)?0:((p<60)?1:2); }

// Quad-pair fragment gather: target lane (quad,colid) builds an A/B-frag word set
// from packed-bf16 accumulator words living on quads {0,1} or {2,3} at same colid.
// pkA = payload when (quad>>1)==0 wanted, pkB = when (quad>>1)==1.
__device__ __forceinline__ short8 fragsel(const u32* pkA, const u32* pkB, int L0, int L1, bool hiq){
  union { u32 w[4]; short8 s; } u;
  u32 a, b;
  a = (u32)__shfl((int)pkA[0], L0); b = (u32)__shfl((int)pkB[0], L0); u.w[0] = hiq ? b : a;
  a = (u32)__shfl((int)pkA[1], L0); b = (u32)__shfl((int)pkB[1], L0); u.w[1] = hiq ? b : a;
  a = (u32)__shfl((int)pkA[0], L1); b = (u32)__shfl((int)pkB[0], L1); u.w[2] = hiq ? b : a;
  a = (u32)__shfl((int)pkA[1], L1); b = (u32)__shfl((int)pkB[1], L1); u.w[3] = hiq ? b : a;
  return u.s;
}

// attention kernel LDS: xw[64][264] only (no scratch) -> 33792 B -> 4 blocks/CU by LDS
#define ATTN_ELEMS 16896
// fallback fused kernel LDS
#define SCO 16896
#define FUSED_ELEMS 26112

__global__ void prep_w(const float* __restrict__ wqkv, const float* __restrict__ wo,
                       u16* __restrict__ wqkvT, u16* __restrict__ woT){
  int idx = blockIdx.x*256 + threadIdx.x;
  if(idx < 768*256){ int n = idx>>8, k = idx&255; wqkvT[idx] = f2b(wqkv[k*768 + n]); }
  else { int j = idx - 768*256; int n = j>>8, k = j&255; woT[j] = f2b(wo[k*256 + n]); }
}

// One head: swapped-operand qkv GEMMs + register-only attention.
// Output: opk[m][nq][p] = packed-bf16 O^T, lane holds O^T[ch=m*16+quad*4+{2p,2p+1}][tok=nq*16+colid]
__device__ __forceinline__ void run_head(
    const u16* lds, const u16* __restrict__ wT, const float* __restrict__ bqkv,
    const float* __restrict__ table, int wave, int hi, int colid, int quad,
    int wy, int wx, u32 opk[2][4][2])
{
  const floatx4 fz = {0.f,0.f,0.f,0.f};
  const int h = wave*2 + hi;
  const int L0 = ((quad&1)<<5) + colid, L1 = L0 + 16;
  const bool hiq = quad >= 2;
  const float scale = 0.17677669529663687f;   // 32^-0.5, folded into q

  // ---- q,k swapped GEMMs: acc[ch_tile][tok_tile] = mfma(W-frag, xw-frag) ----
  u32 pkq[2][4][2], pkk[2][4][2];
  #pragma unroll
  for(int cc=0; cc<2; ++cc){
    const int ch0 = (cc*4 + wave)*64 + hi*32;
    const float sc = (cc==0) ? scale : 1.0f;
    floatx4 acc[2][4];
    #pragma unroll
    for(int mt=0;mt<2;++mt)
      #pragma unroll
      for(int nt=0;nt<4;++nt) acc[mt][nt] = fz;
    const u16* wbase = wT + (size_t)(ch0+colid)*256 + quad*8;
    for(int k0=0;k0<256;k0+=32){
      short8 xf[4], wf[2];
      #pragma unroll
      for(int nt=0;nt<4;++nt) xf[nt] = *(const short8*)&lds[(nt*16+colid)*264 + k0 + quad*8];
      #pragma unroll
      for(int mt=0;mt<2;++mt) wf[mt] = *(const short8*)&wbase[(size_t)mt*16*256 + k0];
      #pragma unroll
      for(int mt=0;mt<2;++mt)
        #pragma unroll
        for(int nt=0;nt<4;++nt) acc[mt][nt] = MFMA16(wf[mt], xf[nt], acc[mt][nt]);
    }
    #pragma unroll
    for(int mt=0;mt<2;++mt){
      floatx4 bb = *(const floatx4*)&bqkv[ch0 + mt*16 + quad*4];
      #pragma unroll
      for(int nt=0;nt<4;++nt){
        u32 w0 = pk2((acc[mt][nt][0]+bb[0])*sc, (acc[mt][nt][1]+bb[1])*sc);
        u32 w1 = pk2((acc[mt][nt][2]+bb[2])*sc, (acc[mt][nt][3]+bb[3])*sc);
        if(cc==0){ pkq[mt][nt][0]=w0; pkq[mt][nt][1]=w1; }
        else     { pkk[mt][nt][0]=w0; pkk[mt][nt][1]=w1; }
      }
    }
  }
  short8 qfr[4], kfr[4];
  #pragma unroll
  for(int T=0;T<4;++T){
    qfr[T] = fragsel(pkq[0][T], pkq[1][T], L0, L1, hiq);
    kfr[T] = fragsel(pkk[0][T], pkk[1][T], L0, L1, hiq);
  }

  // ---- v normal GEMM: acc[tok_tile][ch_tile] = mfma(xw-frag, W-frag) ----
  short8 vfr[2][2];
  {
    const int chv = (8 + wave)*64 + hi*32;
    floatx4 acc[4][2];
    #pragma unroll
    for(int mt=0;mt<4;++mt)
      #pragma unroll
      for(int nt=0;nt<2;++nt) acc[mt][nt] = fz;
    const u16* wbase = wT + (size_t)(chv+colid)*256 + quad*8;
    for(int k0=0;k0<256;k0+=32){
      short8 xf[4], wf[2];
      #pragma unroll
      for(int mt=0;mt<4;++mt) xf[mt] = *(const short8*)&lds[(mt*16+colid)*264 + k0 + quad*8];
      #pragma unroll
      for(int nt=0;nt<2;++nt) wf[nt] = *(const short8*)&wbase[(size_t)nt*16*256 + k0];
      #pragma unroll
      for(int mt=0;mt<4;++mt)
        #pragma unroll
        for(int nt=0;nt<2;++nt) acc[mt][nt] = MFMA16(xf[mt], wf[nt], acc[mt][nt]);
    }
    u32 pkv[4][2][2];
    #pragma unroll
    for(int nt=0;nt<2;++nt){
      float bv = bqkv[chv + nt*16 + colid];
      #pragma unroll
      for(int mt=0;mt<4;++mt){
        pkv[mt][nt][0] = pk2(acc[mt][nt][0]+bv, acc[mt][nt][1]+bv);
        pkv[mt][nt][1] = pk2(acc[mt][nt][2]+bv, acc[mt][nt][3]+bv);
      }
    }
    #pragma unroll
    for(int m=0;m<2;++m)
      #pragma unroll
      for(int kc=0;kc<2;++kc)
        vfr[m][kc] = fragsel(pkv[2*kc][m], pkv[2*kc+1][m], L0, L1, hiq);
  }

  // ---- attention: S^T = mfma(K,Q); softmax over tok_k (in-lane 16 + cross-quad) ----
  const int tqx = colid & 7;
  const int rqx = regid(wx*8 + tqx);
  #pragma unroll
  for(int nq=0;nq<4;++nq){
    const int tqy = 2*nq + (colid>>3);
    const int cq = regid(wy*8 + tqy)*3 + rqx;
    floatx4 s4[4];
    #pragma unroll
    for(int mt=0;mt<4;++mt) s4[mt] = MFMA16(kfr[mt], qfr[nq], fz);
    #pragma unroll
    for(int mt=0;mt<4;++mt){
      const int tky = 2*mt + (quad>>1);
      const int ry = (tqy - tky + 7)*15;
      const int rk = regid(wy*8 + tky)*3;
      #pragma unroll
      for(int rr=0;rr<4;++rr){
        const int tkx = (quad&1)*4 + rr;
        const int ck = rk + regid(wx*8 + tkx);
        const int rel = ry + (tqx - tkx + 7);
        s4[mt][rr] += table[rel*8 + h] + ((cq==ck) ? 0.f : -100.f);
      }
    }
    float mx = s4[0][0];
    #pragma unroll
    for(int mt=0;mt<4;++mt)
      #pragma unroll
      for(int rr=0;rr<4;++rr) mx = fmaxf(mx, s4[mt][rr]);
    mx = fmaxf(mx, __shfl_xor(mx, 16));
    mx = fmaxf(mx, __shfl_xor(mx, 32));
    float sum = 0.f;
    #pragma unroll
    for(int mt=0;mt<4;++mt)
      #pragma unroll
      for(int rr=0;rr<4;++rr){ s4[mt][rr] = __expf(s4[mt][rr]-mx); sum += s4[mt][rr]; }
    sum += __shfl_xor(sum, 16);
    sum += __shfl_xor(sum, 32);
    const float inv = 1.0f/sum;
    u32 pkp[4][2];
    #pragma unroll
    for(int mt=0;mt<4;++mt){
      pkp[mt][0] = pk2(s4[mt][0]*inv, s4[mt][1]*inv);
      pkp[mt][1] = pk2(s4[mt][2]*inv, s4[mt][3]*inv);
    }
    short8 pf0 = fragsel(pkp[0], pkp[1], L0, L1, hiq);
    short8 pf1 = fragsel(pkp[2], pkp[3], L0, L1, hiq);
    floatx4 o0 = MFMA16(vfr[0][0], pf0, fz); o0 = MFMA16(vfr[0][1], pf1, o0);
    floatx4 o1 = MFMA16(vfr[1][0], pf0, fz); o1 = MFMA16(vfr[1][1], pf1, o1);
    opk[0][nq][0] = pk2(o0[0], o0[1]); opk[0][nq][1] = pk2(o0[2], o0[3]);
    opk[1][nq][0] = pk2(o1[0], o1[1]); opk[1][nq][1] = pk2(o1[2], o1[3]);
  }
}

// ================= Kernel A: phases 1-3, dump y to workspace =================
__global__ __launch_bounds__(256,3) void swmsa_attn(
    const float* __restrict__ x, const u16* __restrict__ wqkvT, const float* __restrict__ bqkv,
    const float* __restrict__ table, u16* __restrict__ yws)
{
  extern __shared__ u16 lds[];
  const int tid  = threadIdx.x;
  const int wave = tid>>6, lane = tid&63;
  const int quad = lane>>4, colid = lane&15;
  const int bi = blockIdx.x;
  const int xcd = bi & 7, j = bi >> 3;
  const int r0 = ((j >> 3) << 3) | xcd;   // band id = b*8+wy
  const int wx = j & 7;
  const int b = r0 >> 3, wy = r0 & 7;
  const size_t imgbase = (size_t)b*256*4096;
  const int w0 = wx*8+4;

  // ---- Phase 1: gather shifted window, f32->bf16, transpose-pack, xw[tok][ch] ----
  for(int i=0;i<2;++i){
    int unit = tid + 256*i;
    int cg = unit>>3, ty = unit&7;
    int hs = (wy*8+ty+4)&63;
    u16 vv[4][8];
    #pragma unroll
    for(int cc=0;cc<4;++cc){
      const float* src = x + imgbase + (size_t)(cg*4+cc)*4096 + (size_t)hs*64;
      floatx4 lo, hi;
      if(wx<7){ lo = *(const floatx4*)(src+w0); hi = *(const floatx4*)(src+w0+4); }
      else    { lo = *(const floatx4*)(src+60); hi = *(const floatx4*)(src); }
      #pragma unroll
      for(int t=0;t<4;++t){ vv[cc][t]=f2b(lo[t]); vv[cc][4+t]=f2b(hi[t]); }
    }
    #pragma unroll
    for(int t=0;t<8;++t){
      uint64_t pk = (uint64_t)vv[0][t] | ((uint64_t)vv[1][t]<<16)
                  | ((uint64_t)vv[2][t]<<32) | ((uint64_t)vv[3][t]<<48);
      *(uint64_t*)&lds[(ty*8+t)*264 + cg*4] = pk;
    }
  }
  __syncthreads();

  // ---- Phases 2-3, register-resident per head ----
  u32 opk0[2][4][2], opk1[2][4][2];
  run_head(lds, wqkvT, bqkv, table, wave, 0, colid, quad, wy, wx, opk0);
  run_head(lds, wqkvT, bqkv, table, wave, 1, colid, quad, wy, wx, opk1);
  __syncthreads();   // all xw reads done; XW becomes y

  #pragma unroll
  for(int hi=0;hi<2;++hi){
    #pragma unroll
    for(int m=0;m<2;++m)
      #pragma unroll
      for(int nq=0;nq<4;++nq)
        #pragma unroll
        for(int p=0;p<2;++p){
          int row = nq*16 + colid;
          int ch = wave*64 + hi*32 + m*16 + quad*4 + p*2;
          *(u32*)&lds[row*264 + ch] = hi ? opk1[m][nq][p] : opk0[m][nq][p];
        }
  }
  __syncthreads();   // y complete

  // ---- Dump y -> workspace, coalesced 512B rows at the un-shifted image column ----
  const size_t bandbase = (size_t)r0 * (512*256);
  #pragma unroll
  for(int i=0;i<8;++i){
    int unit = i*256 + tid;
    int tokw = unit>>5, c8 = unit&31;
    int tyw = tokw>>3, txw = tokw&7;
    int cg = (8*wx + 4 + txw) & 63;
    size_t t = (size_t)(tyw*64 + cg);
    *(short8*)&yws[bandbase + t*256 + c8*8] = *(const short8*)&lds[tokw*264 + c8*8];
  }
}

// ================= Kernel B: out = y @ w_o + b_o, full-line stores =================
__global__ __launch_bounds__(256,4) void swmsa_proj(
    const u16* __restrict__ yws, const u16* __restrict__ woT,
    const float* __restrict__ bo, float* __restrict__ out)
{
  __shared__ u16 tile[2][256*32];
  const int tid = threadIdx.x;
  const int wave = tid>>6, lane = tid&63;
  const int quad = lane>>4, colid = lane&15;
  const int bi = blockIdx.x;
  const int x7 = bi&7, jj = bi>>3;
  const int band = ((jj>>3)<<3) | x7;
  const int sub = jj&7, h2 = sub>>2, npp = sub&3;
  const int b = band>>3, wy = band&7;
  const u16* ybase = yws + (size_t)band*(512*256) + (size_t)h2*(256*256);
  const int ch = npp*64 + wave*16 + colid;
  const u16* wbase = woT + (size_t)ch*256 + quad*8;
  const floatx4 fzero = {0.f,0.f,0.f,0.f};
  floatx4 acc[16];
  #pragma unroll
  for(int mt=0;mt<16;++mt) acc[mt]=fzero;

  const int rbase0 = tid>>2, slot = tid&3;
  const int swz = (tid>>3)&3;
  const int rsw = (colid>>1)&3;

  short8 sv[4];
  #pragma unroll
  for(int i=0;i<4;++i)
    sv[i] = *(const short8*)&ybase[(size_t)(i*64 + rbase0)*256 + slot*8];
  #pragma unroll
  for(int i=0;i<4;++i)
    *(short8*)&tile[0][(i*64+rbase0)*32 + ((slot^swz))*8] = sv[i];
  __syncthreads();

  for(int kk=0;kk<8;++kk){
    const int cur = kk&1;
    if(kk<7){
      #pragma unroll
      for(int i=0;i<4;++i)
        sv[i] = *(const short8*)&ybase[(size_t)(i*64 + rbase0)*256 + (kk+1)*32 + slot*8];
    }
    short8 bw = *(const short8*)&wbase[kk*32];
    #pragma unroll
    for(int mt=0;mt<16;++mt){
      short8 a = *(const short8*)&tile[cur][(mt*16+colid)*32 + ((quad^rsw))*8];
      acc[mt] = MFMA16(a, bw, acc[mt]);
    }
    if(kk<7){
      #pragma unroll
      for(int i=0;i<4;++i)
        *(short8*)&tile[cur^1][(i*64+rbase0)*32 + ((slot^swz))*8] = sv[i];
    }
    __syncthreads();
  }

  const float bias = bo[ch];
  float* obase = out + (size_t)b*256*4096 + (size_t)ch*4096;
  #pragma unroll
  for(int mt=0;mt<16;++mt){
    int ty = mt>>2;
    int hd = (wy*8 + h2*4 + ty + 4) & 63;
    int colb = (mt&3)*16 + quad*4;
    floatx4 v = acc[mt];
    v[0]+=bias; v[1]+=bias; v[2]+=bias; v[3]+=bias;
    *(floatx4*)(obase + (size_t)hd*64 + colb) = v;
  }
}

// ================= Fallback: round-1 fused kernel (if workspace too small) =================
__global__ __launch_bounds__(256,3) void swmsa_fused(
    const float* __restrict__ x, const u16* __restrict__ wqkvT, const float* __restrict__ bqkv,
    const u16* __restrict__ woT, const float* __restrict__ bo, const float* __restrict__ table,
    float* __restrict__ out)
{
  extern __shared__ u16 lds[];
  const int tid  = threadIdx.x;
  const int wave = tid>>6, lane = tid&63;
  const int quad = lane>>4, colid = lane&15;
  const int bi = blockIdx.x;
  const int xcd = bi & 7, j = bi >> 3;
  const int r0 = ((j >> 3) << 3) | xcd;
  const int wx = j & 7;
  const int b = r0 >> 3, wy = r0 & 7;
  const size_t imgbase = (size_t)b*256*4096;
  const int w0 = wx*8+4;
  const floatx4 fzero = {0.f,0.f,0.f,0.f};
  u16* sc = lds + SCO + wave*2304;

  for(int i=0;i<2;++i){
    int unit = tid + 256*i;
    int cg = unit>>3, ty = unit&7;
    int hs = (wy*8+ty+4)&63;
    u16 vv[4][8];
    #pragma unroll
    for(int cc=0;cc<4;++cc){
      const float* src = x + imgbase + (size_t)(cg*4+cc)*4096 + (size_t)hs*64;
      floatx4 lo, hi;
      if(wx<7){ lo = *(const floatx4*)(src+w0); hi = *(const floatx4*)(src+w0+4); }
      else    { lo = *(const floatx4*)(src+60); hi = *(const floatx4*)(src); }
      #pragma unroll
      for(int t=0;t<4;++t){ vv[cc][t]=f2b(lo[t]); vv[cc][4+t]=f2b(hi[t]); }
    }
    #pragma unroll
    for(int t=0;t<8;++t){
      uint64_t pk = (uint64_t)vv[0][t] | ((uint64_t)vv[1][t]<<16)
                  | ((uint64_t)vv[2][t]<<32) | ((uint64_t)vv[3][t]<<48);
      *(uint64_t*)&lds[(ty*8+t)*264 + cg*4] = pk;
    }
  }
  __syncthreads();

  short8 aq2[2][4], bk2[2][4], bv2[2][2][2];
  for(int t3=0; t3<3; ++t3){
    const int cc = 2 - t3;
    const int col0 = (cc*4 + wave)*64;
    const u16* wslab = wqkvT + (size_t)(col0+colid)*256 + quad*8;
    floatx4 acc[4][4];
    #pragma unroll
    for(int mt=0;mt<4;++mt)
      #pragma unroll
      for(int nt=0;nt<4;++nt) acc[mt][nt] = fzero;
    short8 bcur[4], bnxt[4];
    #pragma unroll
    for(int nt=0;nt<4;++nt) bcur[nt] = *(const short8*)&wslab[(size_t)nt*16*256];
    for(int k0=0;k0<256;k0+=32){
      short8 af[4];
      #pragma unroll
      for(int mt=0;mt<4;++mt) af[mt]  = *(const short8*)&lds[(mt*16+colid)*264 + k0 + quad*8];
      if(k0 < 224){
        #pragma unroll
        for(int nt=0;nt<4;++nt) bnxt[nt] = *(const short8*)&wslab[(size_t)nt*16*256 + k0 + 32];
      }
      #pragma unroll
      for(int mt=0;mt<4;++mt)
        #pragma unroll
        for(int nt=0;nt<4;++nt) acc[mt][nt] = MFMA16(af[mt], bcur[nt], acc[mt][nt]);
      #pragma unroll
      for(int nt=0;nt<4;++nt) bcur[nt] = bnxt[nt];
    }
    #pragma unroll
    for(int hf=0; hf<2; ++hf){
      #pragma unroll
      for(int nt2=0; nt2<2; ++nt2){
        int nt = hf*2 + nt2;
        float bias = bqkv[col0 + nt*16 + colid];
        #pragma unroll
        for(int mt=0;mt<4;++mt)
          #pragma unroll
          for(int rr=0;rr<4;++rr){
            int row = mt*16 + quad*4 + rr;
            u16 bvv = f2b(acc[mt][nt][rr] + bias);
            if(cc==2) sc[(nt2*16+colid)*72 + row] = bvv;
            else      sc[row*36 + nt2*16 + colid] = bvv;
          }
      }
      if(cc==2){
        #pragma unroll
        for(int n2=0;n2<2;++n2)
          #pragma unroll
          for(int kc=0;kc<2;++kc)
            bv2[hf][n2][kc] = *(const short8*)&sc[(n2*16+colid)*72 + kc*32 + quad*8];
      } else if(cc==1){
        #pragma unroll
        for(int mt=0;mt<4;++mt) bk2[hf][mt] = *(const short8*)&sc[(mt*16+colid)*36 + quad*8];
      } else {
        #pragma unroll
        for(int mt=0;mt<4;++mt) aq2[hf][mt] = *(const short8*)&sc[(mt*16+colid)*36 + quad*8];
      }
    }
  }
  __syncthreads();

  const float scale = 0.17677669529663687f;
  #pragma unroll
  for(int hi=0; hi<2; ++hi){
    const int h = wave*2 + hi;
    floatx4 s[4][4];
    #pragma unroll
    for(int mt=0;mt<4;++mt)
      #pragma unroll
      for(int nt=0;nt<4;++nt) s[mt][nt] = MFMA16(aq2[hi][mt], bk2[hi][nt], fzero);
    int cntk[4], kys[4], kxs[4];
    #pragma unroll
    for(int nt=0;nt<4;++nt){
      int col = nt*16 + colid;
      kys[nt] = col>>3; kxs[nt] = col&7;
      cntk[nt] = regid(wy*8 + kys[nt])*3 + regid(wx*8 + kxs[nt]);
    }
    #pragma unroll
    for(int mt=0;mt<4;++mt)
      #pragma unroll
      for(int rr=0;rr<4;++rr){
        int row = mt*16 + quad*4 + rr;
        int ty = row>>3, tx = row&7;
        int cntq = regid(wy*8+ty)*3 + regid(wx*8+tx);
        #pragma unroll
        for(int nt=0;nt<4;++nt){
          int rel = (ty - kys[nt] + 7)*15 + (tx - kxs[nt] + 7);
          float add = table[rel*8 + h] + ((cntq==cntk[nt]) ? 0.f : -100.f);
          s[mt][nt][rr] = s[mt][nt][rr]*scale + add;
        }
      }
    u32 gpk[4][4];
    #pragma unroll
    for(int mt=0;mt<4;++mt)
      #pragma unroll
      for(int rr=0;rr<4;++rr){
        float mx = s[mt][0][rr];
        #pragma unroll
        for(int nt=1;nt<4;++nt) mx = fmaxf(mx, s[mt][nt][rr]);
        #pragma unroll
        for(int d=1; d<16; d<<=1) mx = fmaxf(mx, __shfl_xor(mx, d));
        float e[4], sum = 0.f;
        #pragma unroll
        for(int nt=0;nt<4;++nt){ e[nt] = __expf(s[mt][nt][rr]-mx); sum += e[nt]; }
        #pragma unroll
        for(int d=1; d<16; d<<=1) sum += __shfl_xor(sum, d);
        float inv = 1.0f/sum;
        int row = mt*16 + quad*4 + rr;
        sc[row*36 + colid]      = f2b(e[0]*inv);
        sc[row*36 + 16 + colid] = f2b(e[1]*inv);
        gpk[mt][rr] = (u32)f2b(e[2]*inv) | ((u32)f2b(e[3]*inv) << 16);
      }
    floatx4 o[4][2];
    #pragma unroll
    for(int mt=0;mt<4;++mt){ o[mt][0]=fzero; o[mt][1]=fzero; }
    #pragma unroll
    for(int kc=0;kc<2;++kc){
      if(kc==1){
        #pragma unroll
        for(int mt=0;mt<4;++mt)
          #pragma unroll
          for(int rr=0;rr<4;++rr){
            int row = mt*16 + quad*4 + rr;
            sc[row*36 + colid]      = (u16)(gpk[mt][rr] & 0xffffu);
            sc[row*36 + 16 + colid] = (u16)(gpk[mt][rr] >> 16);
          }
      }
      short8 ap[4];
      #pragma unroll
      for(int mt=0;mt<4;++mt) ap[mt] = *(const short8*)&sc[(mt*16+colid)*36 + quad*8];
      #pragma unroll
      for(int mt=0;mt<4;++mt)
        #pragma unroll
        for(int n2=0;n2<2;++n2) o[mt][n2] = MFMA16(ap[mt], bv2[hi][n2][kc], o[mt][n2]);
    }
    #pragma unroll
    for(int n2=0;n2<2;++n2){
      int c = h*32 + n2*16 + colid;
      #pragma unroll
      for(int mt=0;mt<4;++mt)
        #pragma unroll
        for(int rr=0;rr<4;++rr)
          lds[(mt*16+quad*4+rr)*264 + c] = f2b(o[mt][n2][rr]);
    }
  }
  __syncthreads();

  {
    floatx4 acc[4][4];
    #pragma unroll
    for(int np=0;np<4;++np)
      #pragma unroll
      for(int mt=0;mt<4;++mt) acc[np][mt] = fzero;
    const u16* wbase = woT + (size_t)(wave*16+colid)*256 + quad*8;
    for(int k0=0;k0<256;k0+=32){
      short8 ay[4];
      #pragma unroll
      for(int mt=0;mt<4;++mt) ay[mt] = *(const short8*)&lds[(mt*16+colid)*264 + k0 + quad*8];
      #pragma unroll
      for(int np=0;np<4;++np){
        short8 bw = *(const short8*)&wbase[(size_t)np*16384 + k0];
        #pragma unroll
        for(int mt=0;mt<4;++mt) acc[np][mt] = MFMA16(ay[mt], bw, acc[np][mt]);
      }
    }
    const int ty_base = quad>>1, txg = quad&1;
    const int col = (wx<7) ? (w0 + 4*txg) : (txg ? 0 : 60);
    #pragma unroll
    for(int np=0;np<4;++np){
      const int ch = np*64 + wave*16 + colid;
      const float bias = bo[ch];
      float* chbase = out + imgbase + (size_t)ch*4096;
      #pragma unroll
      for(int mt=0;mt<4;++mt){
        int ty = 2*mt + ty_base;
        int hd = (wy*8 + ty + 4)&63;
        floatx4 vsto = acc[np][mt];
        vsto[0]+=bias; vsto[1]+=bias; vsto[2]+=bias; vsto[3]+=bias;
        *(floatx4*)(chbase + (size_t)hd*64 + col) = vsto;
      }
    }
  }
}

extern "C" void kernel_launch(void* const* d_in, const int* in_sizes, int n_in,
                              void* d_out, int out_size, void* d_ws, size_t ws_size,
                              hipStream_t stream) {
  const float* x     = (const float*)d_in[0];
  const float* wqkv  = (const float*)d_in[1];
  const float* bqkv  = (const float*)d_in[2];
  const float* wo    = (const float*)d_in[3];
  const float* bo    = (const float*)d_in[4];
  const float* table = (const float*)d_in[5];
  float* out = (float*)d_out;

  u16* wqkvT = (u16*)d_ws;            // 768x256 bf16
  u16* woT   = wqkvT + 768*256;       // 256x256 bf16
  u16* yws   = woT   + 256*256;       // 256 bands x 512 tok x 256 ch bf16 = 67.1 MB

  const size_t need = (size_t)(768*256 + 256*256)*2 + (size_t)256*512*256*2;

  prep_w<<<1024, 256, 0, stream>>>(wqkv, wo, wqkvT, woT);

  if(ws_size >= need){
    swmsa_attn<<<2048, 256, ATTN_ELEMS*2, stream>>>(x, wqkvT, bqkv, table, yws);
    swmsa_proj<<<2048, 256, 0, stream>>>(yws, woT, bo, out);
  } else {
    (void)hipFuncSetAttribute((const void*)swmsa_fused,
                              hipFuncAttributeMaxDynamicSharedMemorySize, FUSED_ELEMS*2);
    swmsa_fused<<<2048, 256, FUSED_ELEMS*2, stream>>>(x, wqkvT, bqkv, woT, bo, table, out);
  }
}

// Round 7
// 559.259 us; speedup vs baseline: 1.1618x; 1.1618x over previous
//
#include <hip/hip_runtime.h>
#include <stdint.h>

typedef __attribute__((ext_vector_type(8))) short short8;
typedef __attribute__((ext_vector_type(4))) float floatx4;
typedef unsigned short u16;
typedef unsigned int u32;

#define MFMA16(a,b,c) __builtin_amdgcn_mfma_f32_16x16x32_bf16((a),(b),(c),0,0,0)

__device__ __forceinline__ u16 f2b(float f){
  u32 i; __builtin_memcpy(&i,&f,4); i += 0x7FFFu + ((i>>16)&1u); return (u16)(i>>16);
}
__device__ __forceinline__ int regid(int p){ return (p<56)?0:((p<60)?1:2); }

// LDS (u16 elems) for attention kernel, total 26112 elems = 52224 B -> 3 blocks/CU:
//   XW : xw[64][264] (phase 1-2) -> y[64][264] (phase 3)          16896 elems
//   SC : per-wave scratch [64][36] x4                              9216 elems
#define SCO 16896
#define LDS_ELEMS 26112

__global__ void prep_w(const float* __restrict__ wqkv, const float* __restrict__ wo,
                       u16* __restrict__ wqkvT, u16* __restrict__ woT){
  int idx = blockIdx.x*256 + threadIdx.x;
  if(idx < 768*256){ int n = idx>>8, k = idx&255; wqkvT[idx] = f2b(wqkv[k*768 + n]); }
  else { int j = idx - 768*256; int n = j>>8, k = j&255; woT[j] = f2b(wo[k*256 + n]); }
}

// ================= Kernel A: phases 1-3, dump y to workspace =================
// y layout: [band = b*8+wy][t = tyw*64 + img_col][ch 256] bf16 (rows 512B, coalesced)
__global__ __launch_bounds__(256,3) void swmsa_attn(
    const float* __restrict__ x, const u16* __restrict__ wqkvT, const float* __restrict__ bqkv,
    const float* __restrict__ table, u16* __restrict__ yws)
{
  extern __shared__ u16 lds[];
  const int tid  = threadIdx.x;
  const int wave = tid>>6, lane = tid&63;
  const int quad = lane>>4, colid = lane&15;
  // XCD swizzle: 8 windows of one image-row band run consecutively on one XCD
  const int bi = blockIdx.x;
  const int xcd = bi & 7, j = bi >> 3;
  const int r0 = ((j >> 3) << 3) | xcd;   // band id = b*8+wy, 0..255
  const int wx = j & 7;
  const int b = r0 >> 3, wy = r0 & 7;
  const size_t imgbase = (size_t)b*256*4096;
  const int w0 = wx*8+4;
  const floatx4 fzero = {0.f,0.f,0.f,0.f};
  u16* sc = lds + SCO + wave*2304;

  // ---- Phase 1: gather shifted window, f32->bf16, transpose-pack, xw[tok][ch] ----
  for(int i=0;i<2;++i){
    int unit = tid + 256*i;
    int cg = unit>>3, ty = unit&7;
    int hs = (wy*8+ty+4)&63;
    u16 vv[4][8];
    #pragma unroll
    for(int cc=0;cc<4;++cc){
      const float* src = x + imgbase + (size_t)(cg*4+cc)*4096 + (size_t)hs*64;
      floatx4 lo, hi;
      if(wx<7){ lo = *(const floatx4*)(src+w0); hi = *(const floatx4*)(src+w0+4); }
      else    { lo = *(const floatx4*)(src+60); hi = *(const floatx4*)(src); }
      #pragma unroll
      for(int t=0;t<4;++t){ vv[cc][t]=f2b(lo[t]); vv[cc][4+t]=f2b(hi[t]); }
    }
    #pragma unroll
    for(int t=0;t<8;++t){
      uint64_t pk = (uint64_t)vv[0][t] | ((uint64_t)vv[1][t]<<16)
                  | ((uint64_t)vv[2][t]<<32) | ((uint64_t)vv[3][t]<<48);
      *(uint64_t*)&lds[(ty*8+t)*264 + cg*4] = pk;
    }
  }
  __syncthreads();

  // ---- Phase 2: qkv = xw @ w_qkv + b_qkv ----
  short8 aq2[2][4], bk2[2][4], bv2[2][2][2];
  for(int t3=0; t3<3; ++t3){
    const int cc = 2 - t3;                    // v, k, q
    const int col0 = (cc*4 + wave)*64;
    const u16* wslab = wqkvT + (size_t)(col0+colid)*256 + quad*8;
    floatx4 acc[4][4];
    #pragma unroll
    for(int mt=0;mt<4;++mt)
      #pragma unroll
      for(int nt=0;nt<4;++nt) acc[mt][nt] = fzero;
    short8 bcur[4], bnxt[4];
    #pragma unroll
    for(int nt=0;nt<4;++nt) bcur[nt] = *(const short8*)&wslab[(size_t)nt*16*256];
    for(int k0=0;k0<256;k0+=32){
      short8 af[4];
      #pragma unroll
      for(int mt=0;mt<4;++mt) af[mt]  = *(const short8*)&lds[(mt*16+colid)*264 + k0 + quad*8];
      if(k0 < 224){
        #pragma unroll
        for(int nt=0;nt<4;++nt) bnxt[nt] = *(const short8*)&wslab[(size_t)nt*16*256 + k0 + 32];
      }
      #pragma unroll
      for(int mt=0;mt<4;++mt)
        #pragma unroll
        for(int nt=0;nt<4;++nt) acc[mt][nt] = MFMA16(af[mt], bcur[nt], acc[mt][nt]);
      #pragma unroll
      for(int nt=0;nt<4;++nt) bcur[nt] = bnxt[nt];
    }
    #pragma unroll
    for(int hf=0; hf<2; ++hf){
      #pragma unroll
      for(int nt2=0; nt2<2; ++nt2){
        int nt = hf*2 + nt2;
        float bias = bqkv[col0 + nt*16 + colid];
        #pragma unroll
        for(int mt=0;mt<4;++mt)
          #pragma unroll
          for(int rr=0;rr<4;++rr){
            int row = mt*16 + quad*4 + rr;
            u16 bvv = f2b(acc[mt][nt][rr] + bias);
            if(cc==2) sc[(nt2*16+colid)*72 + row] = bvv;     // vt[ch_local][tok]
            else      sc[row*36 + nt2*16 + colid] = bvv;     // [tok][ch_local]
          }
      }
      if(cc==2){
        #pragma unroll
        for(int n2=0;n2<2;++n2)
          #pragma unroll
          for(int kc=0;kc<2;++kc)
            bv2[hf][n2][kc] = *(const short8*)&sc[(n2*16+colid)*72 + kc*32 + quad*8];
      } else if(cc==1){
        #pragma unroll
        for(int mt=0;mt<4;++mt) bk2[hf][mt] = *(const short8*)&sc[(mt*16+colid)*36 + quad*8];
      } else {
        #pragma unroll
        for(int mt=0;mt<4;++mt) aq2[hf][mt] = *(const short8*)&sc[(mt*16+colid)*36 + quad*8];
      }
    }
  }
  __syncthreads();   // all waves done with xw; XW becomes y

  // ---- Phase 3: attention, 2 heads/wave, barrier-free ----
  const float scale = 0.17677669529663687f;  // 32^-0.5
  #pragma unroll
  for(int hi=0; hi<2; ++hi){
    const int h = wave*2 + hi;
    floatx4 s[4][4];
    #pragma unroll
    for(int mt=0;mt<4;++mt)
      #pragma unroll
      for(int nt=0;nt<4;++nt) s[mt][nt] = MFMA16(aq2[hi][mt], bk2[hi][nt], fzero);
    int cntk[4], kys[4], kxs[4];
    #pragma unroll
    for(int nt=0;nt<4;++nt){
      int col = nt*16 + colid;
      kys[nt] = col>>3; kxs[nt] = col&7;
      cntk[nt] = regid(wy*8 + kys[nt])*3 + regid(wx*8 + kxs[nt]);
    }
    #pragma unroll
    for(int mt=0;mt<4;++mt)
      #pragma unroll
      for(int rr=0;rr<4;++rr){
        int row = mt*16 + quad*4 + rr;
        int ty = row>>3, tx = row&7;
        int cntq = regid(wy*8+ty)*3 + regid(wx*8+tx);
        #pragma unroll
        for(int nt=0;nt<4;++nt){
          int rel = (ty - kys[nt] + 7)*15 + (tx - kxs[nt] + 7);
          float add = table[rel*8 + h] + ((cntq==cntk[nt]) ? 0.f : -100.f);
          s[mt][nt][rr] = s[mt][nt][rr]*scale + add;
        }
      }
    u32 gpk[4][4];
    #pragma unroll
    for(int mt=0;mt<4;++mt)
      #pragma unroll
      for(int rr=0;rr<4;++rr){
        float mx = s[mt][0][rr];
        #pragma unroll
        for(int nt=1;nt<4;++nt) mx = fmaxf(mx, s[mt][nt][rr]);
        #pragma unroll
        for(int d=1; d<16; d<<=1) mx = fmaxf(mx, __shfl_xor(mx, d));
        float e[4], sum = 0.f;
        #pragma unroll
        for(int nt=0;nt<4;++nt){ e[nt] = __expf(s[mt][nt][rr]-mx); sum += e[nt]; }
        #pragma unroll
        for(int d=1; d<16; d<<=1) sum += __shfl_xor(sum, d);
        float inv = 1.0f/sum;
        int row = mt*16 + quad*4 + rr;
        sc[row*36 + colid]      = f2b(e[0]*inv);
        sc[row*36 + 16 + colid] = f2b(e[1]*inv);
        gpk[mt][rr] = (u32)f2b(e[2]*inv) | ((u32)f2b(e[3]*inv) << 16);
      }
    floatx4 o[4][2];
    #pragma unroll
    for(int mt=0;mt<4;++mt){ o[mt][0]=fzero; o[mt][1]=fzero; }
    #pragma unroll
    for(int kc=0;kc<2;++kc){
      if(kc==1){
        #pragma unroll
        for(int mt=0;mt<4;++mt)
          #pragma unroll
          for(int rr=0;rr<4;++rr){
            int row = mt*16 + quad*4 + rr;
            sc[row*36 + colid]      = (u16)(gpk[mt][rr] & 0xffffu);
            sc[row*36 + 16 + colid] = (u16)(gpk[mt][rr] >> 16);
          }
      }
      short8 ap[4];
      #pragma unroll
      for(int mt=0;mt<4;++mt) ap[mt] = *(const short8*)&sc[(mt*16+colid)*36 + quad*8];
      #pragma unroll
      for(int mt=0;mt<4;++mt)
        #pragma unroll
        for(int n2=0;n2<2;++n2) o[mt][n2] = MFMA16(ap[mt], bv2[hi][n2][kc], o[mt][n2]);
    }
    // y into XW (wave-own columns)
    #pragma unroll
    for(int n2=0;n2<2;++n2){
      int c = h*32 + n2*16 + colid;
      #pragma unroll
      for(int mt=0;mt<4;++mt)
        #pragma unroll
        for(int rr=0;rr<4;++rr)
          lds[(mt*16+quad*4+rr)*264 + c] = f2b(o[mt][n2][rr]);
    }
  }
  __syncthreads();   // y complete

  // ---- Dump y -> workspace, coalesced 512B rows at the un-shifted image column ----
  const size_t bandbase = (size_t)r0 * (512*256);
  #pragma unroll
  for(int i=0;i<8;++i){
    int unit = i*256 + tid;            // 2048 16B-units (64 tok x 32 chunks)
    int tokw = unit>>5, c8 = unit&31;
    int tyw = tokw>>3, txw = tokw&7;
    int cg = (8*wx + 4 + txw) & 63;    // un-shifted image column
    size_t t = (size_t)(tyw*64 + cg);
    *(short8*)&yws[bandbase + t*256 + c8*8] = *(const short8*)&lds[tokw*264 + c8*8];
  }
}

// ================= Kernel B: out = y @ w_o + b_o, LDS-free, barrier-free =================
// grid 4096: block = (band 256) x (q4: 4 row-pairs) x (npp: 4 ch-quarters).
// A-frags read directly from yws (L2-hot); B-frags from woT. Full 256B-row stores.
__global__ __launch_bounds__(256,2) void swmsa_proj(
    const u16* __restrict__ yws, const u16* __restrict__ woT,
    const float* __restrict__ bo, float* __restrict__ out)
{
  const int tid = threadIdx.x;
  const int wave = tid>>6, lane = tid&63;
  const int quad = lane>>4, colid = lane&15;
  // XCD swizzle: the 16 sub-blocks of a band run on one XCD (share y in L2)
  const int bi = blockIdx.x;
  const int xcd = bi&7, jj = bi>>3;
  const int band = ((jj>>4)<<3) | xcd;         // 0..255
  const int sub = jj&15, q4 = sub>>2, npp = sub&3;
  const int b = band>>3, wy = band&7;
  const u16* ybase = yws + (size_t)band*(512*256) + (size_t)q4*(128*256);
  const int ch = npp*64 + wave*16 + colid;
  const u16* wbase = woT + (size_t)ch*256 + quad*8;
  const u16* abase = ybase + (size_t)colid*256 + quad*8;
  const floatx4 fz = {0.f,0.f,0.f,0.f};
  floatx4 acc[8];
  #pragma unroll
  for(int mt=0;mt<8;++mt) acc[mt]=fz;

  #pragma unroll
  for(int kk=0;kk<8;++kk){
    short8 bw = *(const short8*)&wbase[kk*32];
    #pragma unroll
    for(int mt=0;mt<8;++mt){
      short8 a = *(const short8*)&abase[(size_t)mt*16*256 + kk*32];
      acc[mt] = MFMA16(a, bw, acc[mt]);
    }
  }

  const float bias = bo[ch];
  float* obase = out + (size_t)b*256*4096 + (size_t)ch*4096;
  #pragma unroll
  for(int mt=0;mt<8;++mt){
    int ty = mt>>2;                            // row within pair 0..1
    int hd = (wy*8 + q4*2 + ty + 4) & 63;      // un-shifted image row
    int colb = (mt&3)*16 + quad*4;             // 16B-aligned 4-col chunk
    floatx4 v = acc[mt];
    v[0]+=bias; v[1]+=bias; v[2]+=bias; v[3]+=bias;
    *(floatx4*)(obase + (size_t)hd*64 + colb) = v;
  }
}

// ================= Fallback: round-1 fused kernel (if workspace too small) =================
__global__ __launch_bounds__(256,3) void swmsa_fused(
    const float* __restrict__ x, const u16* __restrict__ wqkvT, const float* __restrict__ bqkv,
    const u16* __restrict__ woT, const float* __restrict__ bo, const float* __restrict__ table,
    float* __restrict__ out)
{
  extern __shared__ u16 lds[];
  const int tid  = threadIdx.x;
  const int wave = tid>>6, lane = tid&63;
  const int quad = lane>>4, colid = lane&15;
  const int bi = blockIdx.x;
  const int xcd = bi & 7, j = bi >> 3;
  const int r0 = ((j >> 3) << 3) | xcd;
  const int wx = j & 7;
  const int b = r0 >> 3, wy = r0 & 7;
  const size_t imgbase = (size_t)b*256*4096;
  const int w0 = wx*8+4;
  const floatx4 fzero = {0.f,0.f,0.f,0.f};
  u16* sc = lds + SCO + wave*2304;

  for(int i=0;i<2;++i){
    int unit = tid + 256*i;
    int cg = unit>>3, ty = unit&7;
    int hs = (wy*8+ty+4)&63;
    u16 vv[4][8];
    #pragma unroll
    for(int cc=0;cc<4;++cc){
      const float* src = x + imgbase + (size_t)(cg*4+cc)*4096 + (size_t)hs*64;
      floatx4 lo, hi;
      if(wx<7){ lo = *(const floatx4*)(src+w0); hi = *(const floatx4*)(src+w0+4); }
      else    { lo = *(const floatx4*)(src+60); hi = *(const floatx4*)(src); }
      #pragma unroll
      for(int t=0;t<4;++t){ vv[cc][t]=f2b(lo[t]); vv[cc][4+t]=f2b(hi[t]); }
    }
    #pragma unroll
    for(int t=0;t<8;++t){
      uint64_t pk = (uint64_t)vv[0][t] | ((uint64_t)vv[1][t]<<16)
                  | ((uint64_t)vv[2][t]<<32) | ((uint64_t)vv[3][t]<<48);
      *(uint64_t*)&lds[(ty*8+t)*264 + cg*4] = pk;
    }
  }
  __syncthreads();

  short8 aq2[2][4], bk2[2][4], bv2[2][2][2];
  for(int t3=0; t3<3; ++t3){
    const int cc = 2 - t3;
    const int col0 = (cc*4 + wave)*64;
    const u16* wslab = wqkvT + (size_t)(col0+colid)*256 + quad*8;
    floatx4 acc[4][4];
    #pragma unroll
    for(int mt=0;mt<4;++mt)
      #pragma unroll
      for(int nt=0;nt<4;++nt) acc[mt][nt] = fzero;
    short8 bcur[4], bnxt[4];
    #pragma unroll
    for(int nt=0;nt<4;++nt) bcur[nt] = *(const short8*)&wslab[(size_t)nt*16*256];
    for(int k0=0;k0<256;k0+=32){
      short8 af[4];
      #pragma unroll
      for(int mt=0;mt<4;++mt) af[mt]  = *(const short8*)&lds[(mt*16+colid)*264 + k0 + quad*8];
      if(k0 < 224){
        #pragma unroll
        for(int nt=0;nt<4;++nt) bnxt[nt] = *(const short8*)&wslab[(size_t)nt*16*256 + k0 + 32];
      }
      #pragma unroll
      for(int mt=0;mt<4;++mt)
        #pragma unroll
        for(int nt=0;nt<4;++nt) acc[mt][nt] = MFMA16(af[mt], bcur[nt], acc[mt][nt]);
      #pragma unroll
      for(int nt=0;nt<4;++nt) bcur[nt] = bnxt[nt];
    }
    #pragma unroll
    for(int hf=0; hf<2; ++hf){
      #pragma unroll
      for(int nt2=0; nt2<2; ++nt2){
        int nt = hf*2 + nt2;
        float bias = bqkv[col0 + nt*16 + colid];
        #pragma unroll
        for(int mt=0;mt<4;++mt)
          #pragma unroll
          for(int rr=0;rr<4;++rr){
            int row = mt*16 + quad*4 + rr;
            u16 bvv = f2b(acc[mt][nt][rr] + bias);
            if(cc==2) sc[(nt2*16+colid)*72 + row] = bvv;
            else      sc[row*36 + nt2*16 + colid] = bvv;
          }
      }
      if(cc==2){
        #pragma unroll
        for(int n2=0;n2<2;++n2)
          #pragma unroll
          for(int kc=0;kc<2;++kc)
            bv2[hf][n2][kc] = *(const short8*)&sc[(n2*16+colid)*72 + kc*32 + quad*8];
      } else if(cc==1){
        #pragma unroll
        for(int mt=0;mt<4;++mt) bk2[hf][mt] = *(const short8*)&sc[(mt*16+colid)*36 + quad*8];
      } else {
        #pragma unroll
        for(int mt=0;mt<4;++mt) aq2[hf][mt] = *(const short8*)&sc[(mt*16+colid)*36 + quad*8];
      }
    }
  }
  __syncthreads();

  const float scale = 0.17677669529663687f;
  #pragma unroll
  for(int hi=0; hi<2; ++hi){
    const int h = wave*2 + hi;
    floatx4 s[4][4];
    #pragma unroll
    for(int mt=0;mt<4;++mt)
      #pragma unroll
      for(int nt=0;nt<4;++nt) s[mt][nt] = MFMA16(aq2[hi][mt], bk2[hi][nt], fzero);
    int cntk[4], kys[4], kxs[4];
    #pragma unroll
    for(int nt=0;nt<4;++nt){
      int col = nt*16 + colid;
      kys[nt] = col>>3; kxs[nt] = col&7;
      cntk[nt] = regid(wy*8 + kys[nt])*3 + regid(wx*8 + kxs[nt]);
    }
    #pragma unroll
    for(int mt=0;mt<4;++mt)
      #pragma unroll
      for(int rr=0;rr<4;++rr){
        int row = mt*16 + quad*4 + rr;
        int ty = row>>3, tx = row&7;
        int cntq = regid(wy*8+ty)*3 + regid(wx*8+tx);
        #pragma unroll
        for(int nt=0;nt<4;++nt){
          int rel = (ty - kys[nt] + 7)*15 + (tx - kxs[nt] + 7);
          float add = table[rel*8 + h] + ((cntq==cntk[nt]) ? 0.f : -100.f);
          s[mt][nt][rr] = s[mt][nt][rr]*scale + add;
        }
      }
    u32 gpk[4][4];
    #pragma unroll
    for(int mt=0;mt<4;++mt)
      #pragma unroll
      for(int rr=0;rr<4;++rr){
        float mx = s[mt][0][rr];
        #pragma unroll
        for(int nt=1;nt<4;++nt) mx = fmaxf(mx, s[mt][nt][rr]);
        #pragma unroll
        for(int d=1; d<16; d<<=1) mx = fmaxf(mx, __shfl_xor(mx, d));
        float e[4], sum = 0.f;
        #pragma unroll
        for(int nt=0;nt<4;++nt){ e[nt] = __expf(s[mt][nt][rr]-mx); sum += e[nt]; }
        #pragma unroll
        for(int d=1; d<16; d<<=1) sum += __shfl_xor(sum, d);
        float inv = 1.0f/sum;
        int row = mt*16 + quad*4 + rr;
        sc[row*36 + colid]      = f2b(e[0]*inv);
        sc[row*36 + 16 + colid] = f2b(e[1]*inv);
        gpk[mt][rr] = (u32)f2b(e[2]*inv) | ((u32)f2b(e[3]*inv) << 16);
      }
    floatx4 o[4][2];
    #pragma unroll
    for(int mt=0;mt<4;++mt){ o[mt][0]=fzero; o[mt][1]=fzero; }
    #pragma unroll
    for(int kc=0;kc<2;++kc){
      if(kc==1){
        #pragma unroll
        for(int mt=0;mt<4;++mt)
          #pragma unroll
          for(int rr=0;rr<4;++rr){
            int row = mt*16 + quad*4 + rr;
            sc[row*36 + colid]      = (u16)(gpk[mt][rr] & 0xffffu);
            sc[row*36 + 16 + colid] = (u16)(gpk[mt][rr] >> 16);
          }
      }
      short8 ap[4];
      #pragma unroll
      for(int mt=0;mt<4;++mt) ap[mt] = *(const short8*)&sc[(mt*16+colid)*36 + quad*8];
      #pragma unroll
      for(int mt=0;mt<4;++mt)
        #pragma unroll
        for(int n2=0;n2<2;++n2) o[mt][n2] = MFMA16(ap[mt], bv2[hi][n2][kc], o[mt][n2]);
    }
    #pragma unroll
    for(int n2=0;n2<2;++n2){
      int c = h*32 + n2*16 + colid;
      #pragma unroll
      for(int mt=0;mt<4;++mt)
        #pragma unroll
        for(int rr=0;rr<4;++rr)
          lds[(mt*16+quad*4+rr)*264 + c] = f2b(o[mt][n2][rr]);
    }
  }
  __syncthreads();

  {
    floatx4 acc[4][4];
    #pragma unroll
    for(int np=0;np<4;++np)
      #pragma unroll
      for(int mt=0;mt<4;++mt) acc[np][mt] = fzero;
    const u16* wbase = woT + (size_t)(wave*16+colid)*256 + quad*8;
    for(int k0=0;k0<256;k0+=32){
      short8 ay[4];
      #pragma unroll
      for(int mt=0;mt<4;++mt) ay[mt] = *(const short8*)&lds[(mt*16+colid)*264 + k0 + quad*8];
      #pragma unroll
      for(int np=0;np<4;++np){
        short8 bw = *(const short8*)&wbase[(size_t)np*16384 + k0];
        #pragma unroll
        for(int mt=0;mt<4;++mt) acc[np][mt] = MFMA16(ay[mt], bw, acc[np][mt]);
      }
    }
    const int ty_base = quad>>1, txg = quad&1;
    const int col = (wx<7) ? (w0 + 4*txg) : (txg ? 0 : 60);
    #pragma unroll
    for(int np=0;np<4;++np){
      const int ch = np*64 + wave*16 + colid;
      const float bias = bo[ch];
      float* chbase = out + imgbase + (size_t)ch*4096;
      #pragma unroll
      for(int mt=0;mt<4;++mt){
        int ty = 2*mt + ty_base;
        int hd = (wy*8 + ty + 4)&63;
        floatx4 vsto = acc[np][mt];
        vsto[0]+=bias; vsto[1]+=bias; vsto[2]+=bias; vsto[3]+=bias;
        *(floatx4*)(chbase + (size_t)hd*64 + col) = vsto;
      }
    }
  }
}

extern "C" void kernel_launch(void* const* d_in, const int* in_sizes, int n_in,
                              void* d_out, int out_size, void* d_ws, size_t ws_size,
                              hipStream_t stream) {
  const float* x     = (const float*)d_in[0];
  const float* wqkv  = (const float*)d_in[1];
  const float* bqkv  = (const float*)d_in[2];
  const float* wo    = (const float*)d_in[3];
  const float* bo    = (const float*)d_in[4];
  const float* table = (const float*)d_in[5];
  float* out = (float*)d_out;

  u16* wqkvT = (u16*)d_ws;            // 768x256 bf16
  u16* woT   = wqkvT + 768*256;       // 256x256 bf16
  u16* yws   = woT   + 256*256;       // 256 bands x 512 tok x 256 ch bf16 = 67.1 MB

  const size_t need = (size_t)(768*256 + 256*256)*2 + (size_t)256*512*256*2;

  prep_w<<<1024, 256, 0, stream>>>(wqkv, wo, wqkvT, woT);

  if(ws_size >= need){
    (void)hipFuncSetAttribute((const void*)swmsa_attn,
                              hipFuncAttributeMaxDynamicSharedMemorySize, LDS_ELEMS*2);
    swmsa_attn<<<2048, 256, LDS_ELEMS*2, stream>>>(x, wqkvT, bqkv, table, yws);
    swmsa_proj<<<4096, 256, 0, stream>>>(yws, woT, bo, out);
  } else {
    (void)hipFuncSetAttribute((const void*)swmsa_fused,
                              hipFuncAttributeMaxDynamicSharedMemorySize, LDS_ELEMS*2);
    swmsa_fused<<<2048, 256, LDS_ELEMS*2, stream>>>(x, wqkvT, bqkv, woT, bo, table, out);
  }
}

// Round 8
// 516.382 us; speedup vs baseline: 1.2582x; 1.0830x over previous
//
#include <hip/hip_runtime.h>
#include <stdint.h>

typedef __attribute__((ext_vector_type(8))) short short8;
typedef __attribute__((ext_vector_type(4))) float floatx4;
typedef unsigned short u16;
typedef unsigned int u32;

#define MFMA16(a,b,c) __builtin_amdgcn_mfma_f32_16x16x32_bf16((a),(b),(c),0,0,0)

__device__ __forceinline__ u16 f2b(float f){
  u32 i; __builtin_memcpy(&i,&f,4); i += 0x7FFFu + ((i>>16)&1u); return (u16)(i>>16);
}
__device__ __forceinline__ int regid(int p){ return (p<56)?0:((p<60)?1:2); }

// LDS (u16 elems) for attention kernel, total 26112 elems = 52224 B -> 3 blocks/CU:
//   XW : xw[64][264] (phase 1-2) -> y[64][264] (phase 3)          16896 elems
//   SC : per-wave scratch [64][36] x4                              9216 elems
#define SCO 16896
#define LDS_ELEMS 26112

__global__ void prep_w(const float* __restrict__ wqkv, const float* __restrict__ wo,
                       u16* __restrict__ wqkvT, u16* __restrict__ woT){
  int idx = blockIdx.x*256 + threadIdx.x;
  if(idx < 768*256){ int n = idx>>8, k = idx&255; wqkvT[idx] = f2b(wqkv[k*768 + n]); }
  else { int j = idx - 768*256; int n = j>>8, k = j&255; woT[j] = f2b(wo[k*256 + n]); }
}

// w_o in MFMA-fragment-major order: woTf[(cht*8+kk)*512 + colid*32 + quad*8 + e]
// for ch = cht*16+colid, k = kk*32+quad*8+e  -> proj B-load is 1KB wave-contiguous.
__global__ void prep_wf(const float* __restrict__ wo, u16* __restrict__ woTf){
  int idx = blockIdx.x*256 + threadIdx.x;    // 65536
  int n = idx>>8, k = idx&255;
  int cht = n>>4, cl = n&15, kk = k>>5, q = (k>>3)&3, e = k&7;
  woTf[(size_t)(cht*8+kk)*512 + cl*32 + q*8 + e] = f2b(wo[k*256 + n]);
}

// ================= Kernel A: phases 1-3, dump y to workspace =================
// y stored FRAGMENT-MAJOR: elem F = (band*256 + (t>>4)*8 + (k>>5))*512 + (t&15)*32
//                                   + ((k>>3)&3)*8 + (k&7)
// so proj's A-fragment load for a (16-tok tile, 32-k chunk) is 1KB wave-contiguous.
__global__ __launch_bounds__(256,3) void swmsa_attn(
    const float* __restrict__ x, const u16* __restrict__ wqkvT, const float* __restrict__ bqkv,
    const float* __restrict__ table, u16* __restrict__ yws)
{
  extern __shared__ u16 lds[];
  const int tid  = threadIdx.x;
  const int wave = tid>>6, lane = tid&63;
  const int quad = lane>>4, colid = lane&15;
  // XCD swizzle: 8 windows of one image-row band run consecutively on one XCD
  const int bi = blockIdx.x;
  const int xcd = bi & 7, j = bi >> 3;
  const int r0 = ((j >> 3) << 3) | xcd;   // band id = b*8+wy, 0..255
  const int wx = j & 7;
  const int b = r0 >> 3, wy = r0 & 7;
  const size_t imgbase = (size_t)b*256*4096;
  const int w0 = wx*8+4;
  const floatx4 fzero = {0.f,0.f,0.f,0.f};
  u16* sc = lds + SCO + wave*2304;

  // ---- Phase 1: gather shifted window, f32->bf16, transpose-pack, xw[tok][ch] ----
  for(int i=0;i<2;++i){
    int unit = tid + 256*i;
    int cg = unit>>3, ty = unit&7;
    int hs = (wy*8+ty+4)&63;
    u16 vv[4][8];
    #pragma unroll
    for(int cc=0;cc<4;++cc){
      const float* src = x + imgbase + (size_t)(cg*4+cc)*4096 + (size_t)hs*64;
      floatx4 lo, hi;
      if(wx<7){ lo = *(const floatx4*)(src+w0); hi = *(const floatx4*)(src+w0+4); }
      else    { lo = *(const floatx4*)(src+60); hi = *(const floatx4*)(src); }
      #pragma unroll
      for(int t=0;t<4;++t){ vv[cc][t]=f2b(lo[t]); vv[cc][4+t]=f2b(hi[t]); }
    }
    #pragma unroll
    for(int t=0;t<8;++t){
      uint64_t pk = (uint64_t)vv[0][t] | ((uint64_t)vv[1][t]<<16)
                  | ((uint64_t)vv[2][t]<<32) | ((uint64_t)vv[3][t]<<48);
      *(uint64_t*)&lds[(ty*8+t)*264 + cg*4] = pk;
    }
  }
  __syncthreads();

  // ---- Phase 2: qkv = xw @ w_qkv + b_qkv ----
  short8 aq2[2][4], bk2[2][4], bv2[2][2][2];
  for(int t3=0; t3<3; ++t3){
    const int cc = 2 - t3;                    // v, k, q
    const int col0 = (cc*4 + wave)*64;
    const u16* wslab = wqkvT + (size_t)(col0+colid)*256 + quad*8;
    floatx4 acc[4][4];
    #pragma unroll
    for(int mt=0;mt<4;++mt)
      #pragma unroll
      for(int nt=0;nt<4;++nt) acc[mt][nt] = fzero;
    short8 bcur[4], bnxt[4];
    #pragma unroll
    for(int nt=0;nt<4;++nt) bcur[nt] = *(const short8*)&wslab[(size_t)nt*16*256];
    for(int k0=0;k0<256;k0+=32){
      short8 af[4];
      #pragma unroll
      for(int mt=0;mt<4;++mt) af[mt]  = *(const short8*)&lds[(mt*16+colid)*264 + k0 + quad*8];
      if(k0 < 224){
        #pragma unroll
        for(int nt=0;nt<4;++nt) bnxt[nt] = *(const short8*)&wslab[(size_t)nt*16*256 + k0 + 32];
      }
      #pragma unroll
      for(int mt=0;mt<4;++mt)
        #pragma unroll
        for(int nt=0;nt<4;++nt) acc[mt][nt] = MFMA16(af[mt], bcur[nt], acc[mt][nt]);
      #pragma unroll
      for(int nt=0;nt<4;++nt) bcur[nt] = bnxt[nt];
    }
    #pragma unroll
    for(int hf=0; hf<2; ++hf){
      #pragma unroll
      for(int nt2=0; nt2<2; ++nt2){
        int nt = hf*2 + nt2;
        float bias = bqkv[col0 + nt*16 + colid];
        #pragma unroll
        for(int mt=0;mt<4;++mt)
          #pragma unroll
          for(int rr=0;rr<4;++rr){
            int row = mt*16 + quad*4 + rr;
            u16 bvv = f2b(acc[mt][nt][rr] + bias);
            if(cc==2) sc[(nt2*16+colid)*72 + row] = bvv;     // vt[ch_local][tok]
            else      sc[row*36 + nt2*16 + colid] = bvv;     // [tok][ch_local]
          }
      }
      if(cc==2){
        #pragma unroll
        for(int n2=0;n2<2;++n2)
          #pragma unroll
          for(int kc=0;kc<2;++kc)
            bv2[hf][n2][kc] = *(const short8*)&sc[(n2*16+colid)*72 + kc*32 + quad*8];
      } else if(cc==1){
        #pragma unroll
        for(int mt=0;mt<4;++mt) bk2[hf][mt] = *(const short8*)&sc[(mt*16+colid)*36 + quad*8];
      } else {
        #pragma unroll
        for(int mt=0;mt<4;++mt) aq2[hf][mt] = *(const short8*)&sc[(mt*16+colid)*36 + quad*8];
      }
    }
  }
  __syncthreads();   // all waves done with xw; XW becomes y

  // ---- Phase 3: attention, 2 heads/wave, barrier-free ----
  const float scale = 0.17677669529663687f;  // 32^-0.5
  #pragma unroll
  for(int hi=0; hi<2; ++hi){
    const int h = wave*2 + hi;
    floatx4 s[4][4];
    #pragma unroll
    for(int mt=0;mt<4;++mt)
      #pragma unroll
      for(int nt=0;nt<4;++nt) s[mt][nt] = MFMA16(aq2[hi][mt], bk2[hi][nt], fzero);
    int cntk[4], kys[4], kxs[4];
    #pragma unroll
    for(int nt=0;nt<4;++nt){
      int col = nt*16 + colid;
      kys[nt] = col>>3; kxs[nt] = col&7;
      cntk[nt] = regid(wy*8 + kys[nt])*3 + regid(wx*8 + kxs[nt]);
    }
    #pragma unroll
    for(int mt=0;mt<4;++mt)
      #pragma unroll
      for(int rr=0;rr<4;++rr){
        int row = mt*16 + quad*4 + rr;
        int ty = row>>3, tx = row&7;
        int cntq = regid(wy*8+ty)*3 + regid(wx*8+tx);
        #pragma unroll
        for(int nt=0;nt<4;++nt){
          int rel = (ty - kys[nt] + 7)*15 + (tx - kxs[nt] + 7);
          float add = table[rel*8 + h] + ((cntq==cntk[nt]) ? 0.f : -100.f);
          s[mt][nt][rr] = s[mt][nt][rr]*scale + add;
        }
      }
    u32 gpk[4][4];
    #pragma unroll
    for(int mt=0;mt<4;++mt)
      #pragma unroll
      for(int rr=0;rr<4;++rr){
        float mx = s[mt][0][rr];
        #pragma unroll
        for(int nt=1;nt<4;++nt) mx = fmaxf(mx, s[mt][nt][rr]);
        #pragma unroll
        for(int d=1; d<16; d<<=1) mx = fmaxf(mx, __shfl_xor(mx, d));
        float e[4], sum = 0.f;
        #pragma unroll
        for(int nt=0;nt<4;++nt){ e[nt] = __expf(s[mt][nt][rr]-mx); sum += e[nt]; }
        #pragma unroll
        for(int d=1; d<16; d<<=1) sum += __shfl_xor(sum, d);
        float inv = 1.0f/sum;
        int row = mt*16 + quad*4 + rr;
        sc[row*36 + colid]      = f2b(e[0]*inv);
        sc[row*36 + 16 + colid] = f2b(e[1]*inv);
        gpk[mt][rr] = (u32)f2b(e[2]*inv) | ((u32)f2b(e[3]*inv) << 16);
      }
    floatx4 o[4][2];
    #pragma unroll
    for(int mt=0;mt<4;++mt){ o[mt][0]=fzero; o[mt][1]=fzero; }
    #pragma unroll
    for(int kc=0;kc<2;++kc){
      if(kc==1){
        #pragma unroll
        for(int mt=0;mt<4;++mt)
          #pragma unroll
          for(int rr=0;rr<4;++rr){
            int row = mt*16 + quad*4 + rr;
            sc[row*36 + colid]      = (u16)(gpk[mt][rr] & 0xffffu);
            sc[row*36 + 16 + colid] = (u16)(gpk[mt][rr] >> 16);
          }
      }
      short8 ap[4];
      #pragma unroll
      for(int mt=0;mt<4;++mt) ap[mt] = *(const short8*)&sc[(mt*16+colid)*36 + quad*8];
      #pragma unroll
      for(int mt=0;mt<4;++mt)
        #pragma unroll
        for(int n2=0;n2<2;++n2) o[mt][n2] = MFMA16(ap[mt], bv2[hi][n2][kc], o[mt][n2]);
    }
    // y into XW (wave-own columns)
    #pragma unroll
    for(int n2=0;n2<2;++n2){
      int c = h*32 + n2*16 + colid;
      #pragma unroll
      for(int mt=0;mt<4;++mt)
        #pragma unroll
        for(int rr=0;rr<4;++rr)
          lds[(mt*16+quad*4+rr)*264 + c] = f2b(o[mt][n2][rr]);
    }
  }
  __syncthreads();   // y complete

  // ---- Dump y -> workspace in fragment-major order ----
  const size_t bandbase = (size_t)r0 * 131072;   // 512 tok x 256 ch
  #pragma unroll
  for(int i=0;i<8;++i){
    int unit = i*256 + tid;            // (tokw 64) x (c8 32)
    int tokw = unit>>5, c8 = unit&31;
    int tyw = tokw>>3, txw = tokw&7;
    int cg = (8*wx + 4 + txw) & 63;    // un-shifted image column
    int t = tyw*64 + cg;
    int kk = c8>>2, q = c8&3;
    size_t dst = bandbase + (size_t)((t>>4)*8 + kk)*512 + (t&15)*32 + q*8;
    *(short8*)&yws[dst] = *(const short8*)&lds[tokw*264 + c8*8];
  }
}

// ================= Kernel B: out = y @ w_o + b_o =================
// grid 4096: block = (band 256) x (q4: 4 row-pairs) x (npp: 4 ch-quarters).
// A and B both fragment-major -> every load is a 1KB wave-contiguous transaction.
// No LDS, no barriers. Full 256B-row stores.
__global__ __launch_bounds__(256,4) void swmsa_proj(
    const u16* __restrict__ yfrag, const u16* __restrict__ woTf,
    const float* __restrict__ bo, float* __restrict__ out)
{
  const int tid = threadIdx.x;
  const int wave = tid>>6, lane = tid&63;
  const int quad = lane>>4, colid = lane&15;
  // XCD swizzle: the 16 sub-blocks of a band run on one XCD (share y in L2)
  const int bi = blockIdx.x;
  const int xcd = bi&7, jj = bi>>3;
  const int band = ((jj>>4)<<3) | xcd;         // 0..255
  const int sub = jj&15, q4 = sub>>2, npp = sub&3;
  const int b = band>>3, wy = band&7;
  const int cht = npp*4 + wave;                // 16-ch tile id
  const u16* abase = yfrag + (size_t)band*131072 + (size_t)(q4*8)*8*512 + colid*32 + quad*8;
  const u16* bbase = woTf + (size_t)(cht*8)*512 + colid*32 + quad*8;
  const floatx4 fz = {0.f,0.f,0.f,0.f};
  floatx4 acc[8];
  #pragma unroll
  for(int mt=0;mt<8;++mt) acc[mt]=fz;

  #pragma unroll
  for(int kk=0;kk<8;++kk){
    short8 bw = *(const short8*)&bbase[kk*512];
    #pragma unroll
    for(int mt=0;mt<8;++mt){
      short8 a = *(const short8*)&abase[(size_t)(mt*8+kk)*512];
      acc[mt] = MFMA16(a, bw, acc[mt]);
    }
  }

  const int ch = cht*16 + colid;
  const float bias = bo[ch];
  float* obase = out + (size_t)b*256*4096 + (size_t)ch*4096;
  #pragma unroll
  for(int mt=0;mt<8;++mt){
    int ty = mt>>2;                            // row within pair 0..1
    int hd = (wy*8 + q4*2 + ty + 4) & 63;      // un-shifted image row
    int colb = (mt&3)*16 + quad*4;             // 16B-aligned 4-col chunk
    floatx4 v = acc[mt];
    v[0]+=bias; v[1]+=bias; v[2]+=bias; v[3]+=bias;
    *(floatx4*)(obase + (size_t)hd*64 + colb) = v;
  }
}

// ================= Fallback: round-1 fused kernel (if workspace too small) =================
__global__ __launch_bounds__(256,3) void swmsa_fused(
    const float* __restrict__ x, const u16* __restrict__ wqkvT, const float* __restrict__ bqkv,
    const u16* __restrict__ woT, const float* __restrict__ bo, const float* __restrict__ table,
    float* __restrict__ out)
{
  extern __shared__ u16 lds[];
  const int tid  = threadIdx.x;
  const int wave = tid>>6, lane = tid&63;
  const int quad = lane>>4, colid = lane&15;
  const int bi = blockIdx.x;
  const int xcd = bi & 7, j = bi >> 3;
  const int r0 = ((j >> 3) << 3) | xcd;
  const int wx = j & 7;
  const int b = r0 >> 3, wy = r0 & 7;
  const size_t imgbase = (size_t)b*256*4096;
  const int w0 = wx*8+4;
  const floatx4 fzero = {0.f,0.f,0.f,0.f};
  u16* sc = lds + SCO + wave*2304;

  for(int i=0;i<2;++i){
    int unit = tid + 256*i;
    int cg = unit>>3, ty = unit&7;
    int hs = (wy*8+ty+4)&63;
    u16 vv[4][8];
    #pragma unroll
    for(int cc=0;cc<4;++cc){
      const float* src = x + imgbase + (size_t)(cg*4+cc)*4096 + (size_t)hs*64;
      floatx4 lo, hi;
      if(wx<7){ lo = *(const floatx4*)(src+w0); hi = *(const floatx4*)(src+w0+4); }
      else    { lo = *(const floatx4*)(src+60); hi = *(const floatx4*)(src); }
      #pragma unroll
      for(int t=0;t<4;++t){ vv[cc][t]=f2b(lo[t]); vv[cc][4+t]=f2b(hi[t]); }
    }
    #pragma unroll
    for(int t=0;t<8;++t){
      uint64_t pk = (uint64_t)vv[0][t] | ((uint64_t)vv[1][t]<<16)
                  | ((uint64_t)vv[2][t]<<32) | ((uint64_t)vv[3][t]<<48);
      *(uint64_t*)&lds[(ty*8+t)*264 + cg*4] = pk;
    }
  }
  __syncthreads();

  short8 aq2[2][4], bk2[2][4], bv2[2][2][2];
  for(int t3=0; t3<3; ++t3){
    const int cc = 2 - t3;
    const int col0 = (cc*4 + wave)*64;
    const u16* wslab = wqkvT + (size_t)(col0+colid)*256 + quad*8;
    floatx4 acc[4][4];
    #pragma unroll
    for(int mt=0;mt<4;++mt)
      #pragma unroll
      for(int nt=0;nt<4;++nt) acc[mt][nt] = fzero;
    short8 bcur[4], bnxt[4];
    #pragma unroll
    for(int nt=0;nt<4;++nt) bcur[nt] = *(const short8*)&wslab[(size_t)nt*16*256];
    for(int k0=0;k0<256;k0+=32){
      short8 af[4];
      #pragma unroll
      for(int mt=0;mt<4;++mt) af[mt]  = *(const short8*)&lds[(mt*16+colid)*264 + k0 + quad*8];
      if(k0 < 224){
        #pragma unroll
        for(int nt=0;nt<4;++nt) bnxt[nt] = *(const short8*)&wslab[(size_t)nt*16*256 + k0 + 32];
      }
      #pragma unroll
      for(int mt=0;mt<4;++mt)
        #pragma unroll
        for(int nt=0;nt<4;++nt) acc[mt][nt] = MFMA16(af[mt], bcur[nt], acc[mt][nt]);
      #pragma unroll
      for(int nt=0;nt<4;++nt) bcur[nt] = bnxt[nt];
    }
    #pragma unroll
    for(int hf=0; hf<2; ++hf){
      #pragma unroll
      for(int nt2=0; nt2<2; ++nt2){
        int nt = hf*2 + nt2;
        float bias = bqkv[col0 + nt*16 + colid];
        #pragma unroll
        for(int mt=0;mt<4;++mt)
          #pragma unroll
          for(int rr=0;rr<4;++rr){
            int row = mt*16 + quad*4 + rr;
            u16 bvv = f2b(acc[mt][nt][rr] + bias);
            if(cc==2) sc[(nt2*16+colid)*72 + row] = bvv;
            else      sc[row*36 + nt2*16 + colid] = bvv;
          }
      }
      if(cc==2){
        #pragma unroll
        for(int n2=0;n2<2;++n2)
          #pragma unroll
          for(int kc=0;kc<2;++kc)
            bv2[hf][n2][kc] = *(const short8*)&sc[(n2*16+colid)*72 + kc*32 + quad*8];
      } else if(cc==1){
        #pragma unroll
        for(int mt=0;mt<4;++mt) bk2[hf][mt] = *(const short8*)&sc[(mt*16+colid)*36 + quad*8];
      } else {
        #pragma unroll
        for(int mt=0;mt<4;++mt) aq2[hf][mt] = *(const short8*)&sc[(mt*16+colid)*36 + quad*8];
      }
    }
  }
  __syncthreads();

  const float scale = 0.17677669529663687f;
  #pragma unroll
  for(int hi=0; hi<2; ++hi){
    const int h = wave*2 + hi;
    floatx4 s[4][4];
    #pragma unroll
    for(int mt=0;mt<4;++mt)
      #pragma unroll
      for(int nt=0;nt<4;++nt) s[mt][nt] = MFMA16(aq2[hi][mt], bk2[hi][nt], fzero);
    int cntk[4], kys[4], kxs[4];
    #pragma unroll
    for(int nt=0;nt<4;++nt){
      int col = nt*16 + colid;
      kys[nt] = col>>3; kxs[nt] = col&7;
      cntk[nt] = regid(wy*8 + kys[nt])*3 + regid(wx*8 + kxs[nt]);
    }
    #pragma unroll
    for(int mt=0;mt<4;++mt)
      #pragma unroll
      for(int rr=0;rr<4;++rr){
        int row = mt*16 + quad*4 + rr;
        int ty = row>>3, tx = row&7;
        int cntq = regid(wy*8+ty)*3 + regid(wx*8+tx);
        #pragma unroll
        for(int nt=0;nt<4;++nt){
          int rel = (ty - kys[nt] + 7)*15 + (tx - kxs[nt] + 7);
          float add = table[rel*8 + h] + ((cntq==cntk[nt]) ? 0.f : -100.f);
          s[mt][nt][rr] = s[mt][nt][rr]*scale + add;
        }
      }
    u32 gpk[4][4];
    #pragma unroll
    for(int mt=0;mt<4;++mt)
      #pragma unroll
      for(int rr=0;rr<4;++rr){
        float mx = s[mt][0][rr];
        #pragma unroll
        for(int nt=1;nt<4;++nt) mx = fmaxf(mx, s[mt][nt][rr]);
        #pragma unroll
        for(int d=1; d<16; d<<=1) mx = fmaxf(mx, __shfl_xor(mx, d));
        float e[4], sum = 0.f;
        #pragma unroll
        for(int nt=0;nt<4;++nt){ e[nt] = __expf(s[mt][nt][rr]-mx); sum += e[nt]; }
        #pragma unroll
        for(int d=1; d<16; d<<=1) sum += __shfl_xor(sum, d);
        float inv = 1.0f/sum;
        int row = mt*16 + quad*4 + rr;
        sc[row*36 + colid]      = f2b(e[0]*inv);
        sc[row*36 + 16 + colid] = f2b(e[1]*inv);
        gpk[mt][rr] = (u32)f2b(e[2]*inv) | ((u32)f2b(e[3]*inv) << 16);
      }
    floatx4 o[4][2];
    #pragma unroll
    for(int mt=0;mt<4;++mt){ o[mt][0]=fzero; o[mt][1]=fzero; }
    #pragma unroll
    for(int kc=0;kc<2;++kc){
      if(kc==1){
        #pragma unroll
        for(int mt=0;mt<4;++mt)
          #pragma unroll
          for(int rr=0;rr<4;++rr){
            int row = mt*16 + quad*4 + rr;
            sc[row*36 + colid]      = (u16)(gpk[mt][rr] & 0xffffu);
            sc[row*36 + 16 + colid] = (u16)(gpk[mt][rr] >> 16);
          }
      }
      short8 ap[4];
      #pragma unroll
      for(int mt=0;mt<4;++mt) ap[mt] = *(const short8*)&sc[(mt*16+colid)*36 + quad*8];
      #pragma unroll
      for(int mt=0;mt<4;++mt)
        #pragma unroll
        for(int n2=0;n2<2;++n2) o[mt][n2] = MFMA16(ap[mt], bv2[hi][n2][kc], o[mt][n2]);
    }
    #pragma unroll
    for(int n2=0;n2<2;++n2){
      int c = h*32 + n2*16 + colid;
      #pragma unroll
      for(int mt=0;mt<4;++mt)
        #pragma unroll
        for(int rr=0;rr<4;++rr)
          lds[(mt*16+quad*4+rr)*264 + c] = f2b(o[mt][n2][rr]);
    }
  }
  __syncthreads();

  {
    floatx4 acc[4][4];
    #pragma unroll
    for(int np=0;np<4;++np)
      #pragma unroll
      for(int mt=0;mt<4;++mt) acc[np][mt] = fzero;
    const u16* wbase = woT + (size_t)(wave*16+colid)*256 + quad*8;
    for(int k0=0;k0<256;k0+=32){
      short8 ay[4];
      #pragma unroll
      for(int mt=0;mt<4;++mt) ay[mt] = *(const short8*)&lds[(mt*16+colid)*264 + k0 + quad*8];
      #pragma unroll
      for(int np=0;np<4;++np){
        short8 bw = *(const short8*)&wbase[(size_t)np*16384 + k0];
        #pragma unroll
        for(int mt=0;mt<4;++mt) acc[np][mt] = MFMA16(ay[mt], bw, acc[np][mt]);
      }
    }
    const int ty_base = quad>>1, txg = quad&1;
    const int col = (wx<7) ? (w0 + 4*txg) : (txg ? 0 : 60);
    #pragma unroll
    for(int np=0;np<4;++np){
      const int ch = np*64 + wave*16 + colid;
      const float bias = bo[ch];
      float* chbase = out + imgbase + (size_t)ch*4096;
      #pragma unroll
      for(int mt=0;mt<4;++mt){
        int ty = 2*mt + ty_base;
        int hd = (wy*8 + ty + 4)&63;
        floatx4 vsto = acc[np][mt];
        vsto[0]+=bias; vsto[1]+=bias; vsto[2]+=bias; vsto[3]+=bias;
        *(floatx4*)(chbase + (size_t)hd*64 + col) = vsto;
      }
    }
  }
}

extern "C" void kernel_launch(void* const* d_in, const int* in_sizes, int n_in,
                              void* d_out, int out_size, void* d_ws, size_t ws_size,
                              hipStream_t stream) {
  const float* x     = (const float*)d_in[0];
  const float* wqkv  = (const float*)d_in[1];
  const float* bqkv  = (const float*)d_in[2];
  const float* wo    = (const float*)d_in[3];
  const float* bo    = (const float*)d_in[4];
  const float* table = (const float*)d_in[5];
  float* out = (float*)d_out;

  u16* wqkvT = (u16*)d_ws;            // 768x256 bf16
  u16* woT   = wqkvT + 768*256;       // 256x256 bf16 (row-major, fused fallback)
  u16* woTf  = woT   + 256*256;       // 256x256 bf16 fragment-major (split path)
  u16* yws   = woTf  + 256*256;       // 256 bands x 512 tok x 256 ch bf16 = 67.1 MB

  const size_t need = (size_t)(768*256 + 256*256 + 256*256)*2 + (size_t)256*512*256*2;

  prep_w<<<1024, 256, 0, stream>>>(wqkv, wo, wqkvT, woT);

  if(ws_size >= need){
    prep_wf<<<256, 256, 0, stream>>>(wo, woTf);
    (void)hipFuncSetAttribute((const void*)swmsa_attn,
                              hipFuncAttributeMaxDynamicSharedMemorySize, LDS_ELEMS*2);
    swmsa_attn<<<2048, 256, LDS_ELEMS*2, stream>>>(x, wqkvT, bqkv, table, yws);
    swmsa_proj<<<4096, 256, 0, stream>>>(yws, woTf, bo, out);
  } else {
    (void)hipFuncSetAttribute((const void*)swmsa_fused,
                              hipFuncAttributeMaxDynamicSharedMemorySize, LDS_ELEMS*2);
    swmsa_fused<<<2048, 256, LDS_ELEMS*2, stream>>>(x, wqkvT, bqkv, woT, bo, table, out);
  }
}